// Round 1
// baseline (344.616 us; speedup 1.0000x reference)
//
#include <hip/hip_runtime.h>
#include <hip/hip_bf16.h>

#define DD 256
#define BB 2048
#define BM 128          // c3 rows per block tile
#define BN 128          // batch columns per iteration
#define LDB 264         // LDS rel-tile stride (elements), +8 pad to spread banks
#define NTILE ((DD * DD) / BM)   // 512 blocks

typedef __bf16 bf16x8 __attribute__((ext_vector_type(8)));
typedef float  f32x4  __attribute__((ext_vector_type(4)));

__device__ __forceinline__ unsigned short f2bf(float f) {
    unsigned int u = __float_as_uint(f);
    return (unsigned short)((u + 0x7FFFu + ((u >> 16) & 1u)) >> 16);  // RNE
}
__device__ __forceinline__ float bf2f(unsigned short s) {
    return __uint_as_float(((unsigned int)s) << 16);
}

// K1: rel = x - offsets, in fp32 (for exact epilogue scaling) and bf16 (MFMA operand)
__global__ void prep_rel(const float* __restrict__ x, const float* __restrict__ offsets,
                         float* __restrict__ rel_f32, unsigned short* __restrict__ rel_bf16) {
    int idx = blockIdx.x * 256 + threadIdx.x;   // B*D = 524288 threads
    int d = idx & (DD - 1);
    float r = x[idx] - offsets[d];
    rel_f32[idx] = r;
    rel_bf16[idx] = f2bf(r);
}

// K2: out[b] = c0 + <c1, rel_b>   (exact fp32; degree-2/3 terms atomicAdd on top)
__global__ void init_out(const float* __restrict__ rel_f32, const float* __restrict__ c1,
                         const float* __restrict__ c0, float* __restrict__ out) {
    int b = blockIdx.x * 256 + threadIdx.x;     // 2048 threads
    const float4* rp = (const float4*)(rel_f32 + (size_t)b * DD);
    const float4* cp = (const float4*)c1;
    float s = c0[0];
#pragma unroll 8
    for (int i = 0; i < DD / 4; ++i) {
        float4 r = rp[i]; float4 c = cp[i];
        s += r.x * c.x + r.y * c.y + r.z * c.z + r.w * c.w;
    }
    out[b] = s;
}

// K3: fused GEMM (c3 reshaped (D^2 x D) @ rel^T) + c2 fold + weighted reduction.
// Block = one 128-row tile of c3: rows ij = tile*128 + rl, i = tile>>1 (const), j = jbase + rl.
// out[b] += r[b,i] * sum_rl r[b, jbase+rl] * (G[rl,b] + c2[i, jbase+rl])
__global__ __launch_bounds__(256, 1) void taylor3(
    const float* __restrict__ c3, const float* __restrict__ c2,
    const float* __restrict__ rel_f32, const unsigned short* __restrict__ rel_bf16,
    float* __restrict__ out)
{
    __shared__ unsigned short Bs[BN * LDB];   // 67,584 B rel tile (bf16, padded rows)
    __shared__ float colsum2[2 * BN];         // per-wave_m column partials

    const int tile = blockIdx.x;
    const int i_t   = tile >> 1;
    const int jbase = (tile & 1) << 7;        // 0 or 128
    const int tid  = threadIdx.x;
    const int wave = tid >> 6;                // 4 waves: 2x2 grid of 64x64 sub-tiles
    const int lane = tid & 63;
    const int wm = wave & 1, wn = wave >> 1;
    const int lrow = lane & 15, quad = lane >> 4;

    // ---- hoist A fragments to registers (once per block, reused over 16 b-tiles) ----
    // afr[ks][mt]: A[m = wm*64+mt*16+lrow][k = ks*32 + quad*8 + j], fp32->bf16 on the fly
    bf16x8 afr[8][4];
    {
        const float* abase = c3 + (size_t)tile * BM * DD;
#pragma unroll
        for (int mt = 0; mt < 4; ++mt) {
            const int row = wm * 64 + mt * 16 + lrow;
            const float* p = abase + (size_t)row * DD + quad * 8;
#pragma unroll
            for (int ks = 0; ks < 8; ++ks) {
                float4 f0 = *(const float4*)(p + ks * 32);
                float4 f1 = *(const float4*)(p + ks * 32 + 4);
                union { unsigned short u[8]; bf16x8 v; } cv;
                cv.u[0] = f2bf(f0.x); cv.u[1] = f2bf(f0.y);
                cv.u[2] = f2bf(f0.z); cv.u[3] = f2bf(f0.w);
                cv.u[4] = f2bf(f1.x); cv.u[5] = f2bf(f1.y);
                cv.u[6] = f2bf(f1.z); cv.u[7] = f2bf(f1.w);
                afr[ks][mt] = cv.v;
            }
        }
    }
    // c2 values for this lane's 16 output rows (C/D layout: row = quad*4+reg)
    float c2v[4][4];
#pragma unroll
    for (int mt = 0; mt < 4; ++mt)
#pragma unroll
        for (int r = 0; r < 4; ++r)
            c2v[mt][r] = c2[i_t * DD + jbase + wm * 64 + mt * 16 + quad * 4 + r];

    for (int nb = 0; nb < BB / BN; ++nb) {
        const int b0 = nb * BN;
        __syncthreads();   // previous iter's Bs/colsum2 readers done
        // ---- stage rel tile: 128 b-rows x 256 k, bf16, 16B chunks, coalesced ----
#pragma unroll
        for (int c = 0; c < (BN * DD / 8) / 256; ++c) {
            int ch = c * 256 + tid;
            int rr = ch >> 5;
            int kc = (ch & 31) << 3;
            uint4 v = *(const uint4*)(rel_bf16 + (size_t)(b0 + rr) * DD + kc);
            *(uint4*)(&Bs[rr * LDB + kc]) = v;
        }
        __syncthreads();

        f32x4 acc[4][4];
#pragma unroll
        for (int mt = 0; mt < 4; ++mt)
#pragma unroll
            for (int nt = 0; nt < 4; ++nt)
                acc[mt][nt] = (f32x4){0.f, 0.f, 0.f, 0.f};

        // ---- K-loop: 8 steps of 16x16x32, 16 MFMA + 4 ds_read_b128 per step per wave ----
#pragma unroll
        for (int ks = 0; ks < 8; ++ks) {
            bf16x8 bfr[4];
#pragma unroll
            for (int nt = 0; nt < 4; ++nt) {
                int col = wn * 64 + nt * 16 + lrow;
                bfr[nt] = *(const bf16x8*)(&Bs[col * LDB + ks * 32 + quad * 8]);
            }
#pragma unroll
            for (int mt = 0; mt < 4; ++mt)
#pragma unroll
                for (int nt = 0; nt < 4; ++nt)
                    acc[mt][nt] = __builtin_amdgcn_mfma_f32_16x16x32_bf16(
                        afr[ks][mt], bfr[nt], acc[mt][nt], 0, 0, 0);
        }

        // ---- epilogue: s(col) = sum_rows (G + c2) * r[b, j(row)], reduce quads ----
#pragma unroll
        for (int nt = 0; nt < 4; ++nt) {
            const int col = wn * 64 + nt * 16 + lrow;
            float s = 0.f;
#pragma unroll
            for (int mt = 0; mt < 4; ++mt) {
                const ushort4 rj = *(const ushort4*)(
                    &Bs[col * LDB + jbase + wm * 64 + mt * 16 + quad * 4]);
                s += (acc[mt][nt][0] + c2v[mt][0]) * bf2f(rj.x);
                s += (acc[mt][nt][1] + c2v[mt][1]) * bf2f(rj.y);
                s += (acc[mt][nt][2] + c2v[mt][2]) * bf2f(rj.z);
                s += (acc[mt][nt][3] + c2v[mt][3]) * bf2f(rj.w);
            }
            s += __shfl_xor(s, 16, 64);
            s += __shfl_xor(s, 32, 64);
            if (quad == 0) colsum2[wm * BN + col] = s;   // unique (wm,col) writer
        }
        __syncthreads();
        if (tid < BN) {
            float relI = rel_f32[(size_t)(b0 + tid) * DD + i_t];  // fp32 for accuracy
            atomicAdd(&out[b0 + tid], relI * (colsum2[tid] + colsum2[BN + tid]));
        }
    }
}

extern "C" void kernel_launch(void* const* d_in, const int* in_sizes, int n_in,
                              void* d_out, int out_size, void* d_ws, size_t ws_size,
                              hipStream_t stream) {
    const float* x       = (const float*)d_in[0];
    const float* offsets = (const float*)d_in[1];
    const float* c0      = (const float*)d_in[2];
    const float* c1      = (const float*)d_in[3];
    const float* c2      = (const float*)d_in[4];
    const float* c3      = (const float*)d_in[5];
    float* out = (float*)d_out;

    float* rel_f32 = (float*)d_ws;                                        // 2 MB
    unsigned short* rel_bf16 = (unsigned short*)((char*)d_ws + (size_t)BB * DD * 4); // 1 MB

    prep_rel<<<(BB * DD) / 256, 256, 0, stream>>>(x, offsets, rel_f32, rel_bf16);
    init_out<<<BB / 256, 256, 0, stream>>>(rel_f32, c1, c0, out);
    taylor3<<<NTILE, 256, 0, stream>>>(c3, c2, rel_f32, rel_bf16, out);
}

// Round 2
// 234.475 us; speedup vs baseline: 1.4697x; 1.4697x over previous
//
#include <hip/hip_runtime.h>
#include <hip/hip_bf16.h>

#define DD 256
#define BB 2048
#define BM 128                   // c3 rows per block tile
#define BN 64                    // batch columns per pipeline stage
#define NTILE ((DD * DD) / BM)   // 512 blocks
#define NSTAGE (BB / BN)         // 32 pipeline iterations

typedef __bf16 bf16x8 __attribute__((ext_vector_type(8)));
typedef float  f32x4  __attribute__((ext_vector_type(4)));

#define AS1 __attribute__((address_space(1)))
#define AS3 __attribute__((address_space(3)))

__device__ __forceinline__ unsigned short f2bf(float f) {
    unsigned int u = __float_as_uint(f);
    return (unsigned short)((u + 0x7FFFu + ((u >> 16) & 1u)) >> 16);  // RNE
}
__device__ __forceinline__ float bf2f(unsigned short s) {
    return __uint_as_float(((unsigned int)s) << 16);
}
__device__ __forceinline__ void async_cp16(const void* g, void* l) {
    __builtin_amdgcn_global_load_lds((const AS1 unsigned int*)g,
                                     (AS3 unsigned int*)l, 16, 0, 0);
}

// K1: rel = x - offsets, fp32 (epilogue scaling) + bf16 (MFMA operand)
__global__ void prep_rel(const float* __restrict__ x, const float* __restrict__ offsets,
                         float* __restrict__ rel_f32, unsigned short* __restrict__ rel_bf16) {
    int idx = blockIdx.x * 256 + threadIdx.x;
    int d = idx & (DD - 1);
    float r = x[idx] - offsets[d];
    rel_f32[idx] = r;
    rel_bf16[idx] = f2bf(r);
}

// K2: out[b] = c0 + <c1, rel_b>  (exact fp32)
__global__ void init_out(const float* __restrict__ rel_f32, const float* __restrict__ c1,
                         const float* __restrict__ c0, float* __restrict__ out) {
    int b = blockIdx.x * 256 + threadIdx.x;
    const float4* rp = (const float4*)(rel_f32 + (size_t)b * DD);
    const float4* cp = (const float4*)c1;
    float s = c0[0];
#pragma unroll 8
    for (int i = 0; i < DD / 4; ++i) {
        float4 r = rp[i]; float4 c = cp[i];
        s += r.x * c.x + r.y * c.y + r.z * c.z + r.w * c.w;
    }
    out[b] = s;
}

// K3: fused GEMM (c3 tile @ rel^T) + c2 fold + weighted column reduction -> partial[1024][2048]
// LDS layout: Bs[buf][row][phys_granule], phys = logical_granule ^ (row & 7)  (swizzle, no pad)
__global__ __launch_bounds__(256, 2) void taylor3(
    const float* __restrict__ c3, const float* __restrict__ c2,
    const float* __restrict__ rel_f32, const unsigned short* __restrict__ rel_bf16,
    float* __restrict__ partial)
{
    __shared__ unsigned short Bs[2][BN * DD];   // 2 x 32 KB, double-buffered

    const int tile = blockIdx.x;
    const int i_t   = tile >> 1;
    const int jbase = (tile & 1) << 7;
    const int tid  = threadIdx.x;
    const int wave = tid >> 6;
    const int lane = tid & 63;
    const int wm = wave & 1, wn = wave >> 1;    // 2x2: wm = 64-row half, wn = 32-col half
    const int lrow = lane & 15, quad = lane >> 4;

    // ---- hoist A fragments (c3 tile) to registers: afr[ks][mt] ----
    bf16x8 afr[8][4];
    {
        const float* abase = c3 + (size_t)tile * BM * DD;
#pragma unroll
        for (int mt = 0; mt < 4; ++mt) {
            const int row = wm * 64 + mt * 16 + lrow;
            const float* p = abase + (size_t)row * DD + quad * 8;
#pragma unroll
            for (int ks = 0; ks < 8; ++ks) {
                float4 f0 = *(const float4*)(p + ks * 32);
                float4 f1 = *(const float4*)(p + ks * 32 + 4);
                union { unsigned short u[8]; bf16x8 v; } cv;
                cv.u[0] = f2bf(f0.x); cv.u[1] = f2bf(f0.y);
                cv.u[2] = f2bf(f0.z); cv.u[3] = f2bf(f0.w);
                cv.u[4] = f2bf(f1.x); cv.u[5] = f2bf(f1.y);
                cv.u[6] = f2bf(f1.z); cv.u[7] = f2bf(f1.w);
                afr[ks][mt] = cv.v;
            }
        }
    }
    // c2 for this lane's 16 output rows (C/D layout: row = quad*4 + reg)
    float c2v[4][4];
#pragma unroll
    for (int mt = 0; mt < 4; ++mt)
#pragma unroll
        for (int r = 0; r < 4; ++r)
            c2v[mt][r] = c2[i_t * DD + jbase + wm * 64 + mt * 16 + quad * 4 + r];

    // ---- async stage: tile nb -> Bs[buf]; 8 x 1KB per wave, swizzled dest ----
    auto stage = [&](int nb, int buf) {
        const int b0 = nb * BN;
#pragma unroll
        for (int c = 0; c < 8; ++c) {
            const int r0 = wave * 16 + c * 2;           // wave-uniform base row
            const int row = r0 + (lane >> 5);
            const int g = (lane & 31) ^ (row & 7);      // logical granule for this phys slot
            const unsigned short* src = rel_bf16 + (size_t)(b0 + row) * DD + g * 8;
            async_cp16(src, &Bs[buf][r0 * DD]);         // lane L -> base + L*16 bytes
        }
    };

    stage(0, 0);

    for (int nb = 0; nb < NSTAGE; ++nb) {
        const int cur = nb & 1;
        const int b0 = nb * BN;
        __syncthreads();          // drains async loads of Bs[cur]; WAR-protects Bs[cur^1]
        if (nb + 1 < NSTAGE) stage(nb + 1, cur ^ 1);   // in flight across K-loop

        f32x4 acc[4][2];
#pragma unroll
        for (int mt = 0; mt < 4; ++mt)
#pragma unroll
            for (int nt = 0; nt < 2; ++nt)
                acc[mt][nt] = (f32x4){0.f, 0.f, 0.f, 0.f};

        // ---- K-loop: 8 steps of 16x16x32 over Bs[cur] ----
#pragma unroll
        for (int ks = 0; ks < 8; ++ks) {
            bf16x8 bfr[2];
#pragma unroll
            for (int nt = 0; nt < 2; ++nt) {
                const int col = wn * 32 + nt * 16 + lrow;
                const int g = (ks * 4 + quad) ^ (col & 7);
                bfr[nt] = *(const bf16x8*)(&Bs[cur][col * DD + g * 8]);
            }
#pragma unroll
            for (int mt = 0; mt < 4; ++mt)
#pragma unroll
                for (int nt = 0; nt < 2; ++nt)
                    acc[mt][nt] = __builtin_amdgcn_mfma_f32_16x16x32_bf16(
                        afr[ks][mt], bfr[nt], acc[mt][nt], 0, 0, 0);
        }

        // ---- epilogue: s(col) = sum_rows (G + c2) * r[b, j(row)]; fold r_i; store ----
        float sv[2];
#pragma unroll
        for (int nt = 0; nt < 2; ++nt) {
            const int col = wn * 32 + nt * 16 + lrow;
            float s = 0.f;
#pragma unroll
            for (int mt = 0; mt < 4; ++mt) {
                const int e = jbase + wm * 64 + mt * 16 + quad * 4;   // j-element index
                const int g = (e >> 3) ^ (col & 7);
                const ushort4 rj = *(const ushort4*)(&Bs[cur][col * DD + g * 8 + (e & 7)]);
                s += (acc[mt][nt][0] + c2v[mt][0]) * bf2f(rj.x);
                s += (acc[mt][nt][1] + c2v[mt][1]) * bf2f(rj.y);
                s += (acc[mt][nt][2] + c2v[mt][2]) * bf2f(rj.z);
                s += (acc[mt][nt][3] + c2v[mt][3]) * bf2f(rj.w);
            }
            s += __shfl_xor(s, 16, 64);
            s += __shfl_xor(s, 32, 64);
            sv[nt] = s;
        }
        if (lane < 32) {
            const int colS = wn * 32 + lane;            // contiguous 32 cols per wave
            const float relI = rel_f32[(size_t)(b0 + colS) * DD + i_t];
            partial[(size_t)(tile * 2 + wm) * BB + b0 + colS] = relI * sv[lane >> 4];
        }
    }
}

// K4: out[b] += sum_r partial[r][b]   (1024 rows)
__global__ void reduce_partial(const float* __restrict__ partial, float* __restrict__ out) {
    __shared__ float4 red[256];
    const int t = threadIdx.x;
    const int g4 = blockIdx.x * 32 + (t & 31);   // float4 column group, 512 total
    const int rs = t >> 5;                       // 8 row-slices of 128
    float4 s = {0.f, 0.f, 0.f, 0.f};
    for (int r = rs * 128; r < rs * 128 + 128; ++r) {
        float4 v = *(const float4*)(partial + (size_t)r * BB + g4 * 4);
        s.x += v.x; s.y += v.y; s.z += v.z; s.w += v.w;
    }
    red[t] = s; __syncthreads();
    if (t < 128) { float4 o = red[t + 128]; red[t].x += o.x; red[t].y += o.y; red[t].z += o.z; red[t].w += o.w; }
    __syncthreads();
    if (t < 64)  { float4 o = red[t + 64];  red[t].x += o.x; red[t].y += o.y; red[t].z += o.z; red[t].w += o.w; }
    __syncthreads();
    if (t < 32) {
        float4 a = red[t]; float4 b = red[t + 32];
        float4* op = (float4*)(out + (size_t)g4 * 4);
        float4 o = *op;
        o.x += a.x + b.x; o.y += a.y + b.y; o.z += a.z + b.z; o.w += a.w + b.w;
        *op = o;
    }
}

extern "C" void kernel_launch(void* const* d_in, const int* in_sizes, int n_in,
                              void* d_out, int out_size, void* d_ws, size_t ws_size,
                              hipStream_t stream) {
    const float* x       = (const float*)d_in[0];
    const float* offsets = (const float*)d_in[1];
    const float* c0      = (const float*)d_in[2];
    const float* c1      = (const float*)d_in[3];
    const float* c2      = (const float*)d_in[4];
    const float* c3      = (const float*)d_in[5];
    float* out = (float*)d_out;

    char* ws = (char*)d_ws;
    float* rel_f32 = (float*)ws;                                   // 2 MB
    unsigned short* rel_bf16 = (unsigned short*)(ws + (size_t)BB * DD * 4);  // 1 MB
    float* partial = (float*)(ws + (size_t)BB * DD * 6);           // 8 MB (1024 x 2048 f32)

    prep_rel<<<(BB * DD) / 256, 256, 0, stream>>>(x, offsets, rel_f32, rel_bf16);
    init_out<<<BB / 256, 256, 0, stream>>>(rel_f32, c1, c0, out);
    taylor3<<<NTILE, 256, 0, stream>>>(c3, c2, rel_f32, rel_bf16, partial);
    reduce_partial<<<16, 256, 0, stream>>>(partial, out);
}

// Round 4
// 221.729 us; speedup vs baseline: 1.5542x; 1.0575x over previous
//
#include <hip/hip_runtime.h>
#include <hip/hip_bf16.h>

#define DD 256
#define BB 2048
#define BM 128                   // c3 rows per block tile
#define BN 64                    // batch columns per pipeline stage
#define NTILE ((DD * DD) / BM)   // 512 blocks
#define NSTAGE (BB / BN)         // 32 pipeline iterations

typedef __bf16 bf16x8 __attribute__((ext_vector_type(8)));
typedef float  f32x4  __attribute__((ext_vector_type(4)));

#define AS1 __attribute__((address_space(1)))
#define AS3 __attribute__((address_space(3)))

__device__ __forceinline__ unsigned short f2bf(float f) {
    unsigned int u = __float_as_uint(f);
    return (unsigned short)((u + 0x7FFFu + ((u >> 16) & 1u)) >> 16);  // RNE
}
__device__ __forceinline__ float bf2f(unsigned short s) {
    return __uint_as_float(((unsigned int)s) << 16);
}
__device__ __forceinline__ void async_cp16(const void* g, void* l) {
    __builtin_amdgcn_global_load_lds((const AS1 unsigned int*)g,
                                     (AS3 unsigned int*)l, 16, 0, 0);
}

// K1: fused rel = x - offsets (fp32 + bf16) and out[b] = c0 + <c1, rel_b>
// 256 blocks x 256 threads; each wave handles 2 b-rows (64 lanes x float4 = 256 elems)
__global__ void prep_all(const float* __restrict__ x, const float* __restrict__ offsets,
                         const float* __restrict__ c0, const float* __restrict__ c1,
                         float* __restrict__ rel_f32, unsigned short* __restrict__ rel_bf16,
                         float* __restrict__ out) {
    const int tid = threadIdx.x, wave = tid >> 6, lane = tid & 63;
    const float4 o4  = *(const float4*)(offsets + lane * 4);
    const float4 c14 = *(const float4*)(c1 + lane * 4);
#pragma unroll
    for (int i = 0; i < 2; ++i) {
        const int b = blockIdx.x * 8 + wave * 2 + i;
        const float4 x4 = *(const float4*)(x + (size_t)b * DD + lane * 4);
        float4 r;
        r.x = x4.x - o4.x; r.y = x4.y - o4.y; r.z = x4.z - o4.z; r.w = x4.w - o4.w;
        *(float4*)(rel_f32 + (size_t)b * DD + lane * 4) = r;
        ushort4 rb;
        rb.x = f2bf(r.x); rb.y = f2bf(r.y); rb.z = f2bf(r.z); rb.w = f2bf(r.w);
        *(ushort4*)(rel_bf16 + (size_t)b * DD + lane * 4) = rb;
        float s = r.x * c14.x + r.y * c14.y + r.z * c14.z + r.w * c14.w;
        s += __shfl_xor(s, 1);  s += __shfl_xor(s, 2);  s += __shfl_xor(s, 4);
        s += __shfl_xor(s, 8);  s += __shfl_xor(s, 16); s += __shfl_xor(s, 32);
        if (lane == 0) out[b] = c0[0] + s;
    }
}

// K3: fused GEMM (c3 tile @ rel^T) + c2 fold + weighted column reduction.
// 512 threads = 8 waves in 4(row-slice) x 2(col-half) grid; each wave 32 rows x 32 cols.
// In-block cross-wave combine via double-buffered colsum -> partial[512][2048].
__global__ __launch_bounds__(512, 4) void taylor3(
    const float* __restrict__ c3, const float* __restrict__ c2,
    const float* __restrict__ rel_f32, const unsigned short* __restrict__ rel_bf16,
    float* __restrict__ partial)
{
    __shared__ unsigned short Bs[2][BN * DD];   // 2 x 32 KB, double-buffered
    __shared__ float relI[BB];                  // 8 KB: rel[:, i_t]
    __shared__ float colsum[2][4][BN];          // 2 KB, double-buffered per-wm partials

    const int tile = blockIdx.x;
    const int i_t   = tile >> 1;
    const int jbase = (tile & 1) << 7;
    const int tid  = threadIdx.x;
    const int wave = tid >> 6;
    const int lane = tid & 63;
    const int wm = wave & 3, wn = wave >> 2;
    const int lrow = lane & 15, quad = lane >> 4;

    // stage rel[:, i_t] into LDS (one-time strided gather)
#pragma unroll
    for (int k = 0; k < 4; ++k) {
        const int b = tid + k * 512;
        relI[b] = rel_f32[(size_t)b * DD + i_t];
    }

    // ---- hoist A fragments (c3, 32 rows/wave x 256 k) to registers ----
    bf16x8 afr[8][2];
    {
        const float* abase = c3 + (size_t)tile * BM * DD;
#pragma unroll
        for (int mt = 0; mt < 2; ++mt) {
            const int row = wm * 32 + mt * 16 + lrow;
            const float* p = abase + (size_t)row * DD + quad * 8;
#pragma unroll
            for (int ks = 0; ks < 8; ++ks) {
                float4 f0 = *(const float4*)(p + ks * 32);
                float4 f1 = *(const float4*)(p + ks * 32 + 4);
                union { unsigned short u[8]; bf16x8 v; } cv;
                cv.u[0] = f2bf(f0.x); cv.u[1] = f2bf(f0.y);
                cv.u[2] = f2bf(f0.z); cv.u[3] = f2bf(f0.w);
                cv.u[4] = f2bf(f1.x); cv.u[5] = f2bf(f1.y);
                cv.u[6] = f2bf(f1.z); cv.u[7] = f2bf(f1.w);
                afr[ks][mt] = cv.v;
            }
        }
    }
    // c2 for this lane's 8 output rows (C/D layout: row = quad*4 + reg)
    float c2v[2][4];
#pragma unroll
    for (int mt = 0; mt < 2; ++mt)
#pragma unroll
        for (int r = 0; r < 4; ++r)
            c2v[mt][r] = c2[i_t * DD + jbase + wm * 32 + mt * 16 + quad * 4 + r];

    // ---- async stage: tile nb -> Bs[buf]; 4 rounds x 16 rows, swizzled granules ----
    auto stage = [&](int nb, int buf) {
        const int b0 = nb * BN;
#pragma unroll
        for (int c = 0; c < 4; ++c) {
            const int r0 = c * 16 + wave * 2;           // wave-uniform base row
            const int row = r0 + (lane >> 5);
            const int g = (lane & 31) ^ (row & 7);      // logical granule for this phys slot
            const unsigned short* src = rel_bf16 + (size_t)(b0 + row) * DD + g * 8;
            async_cp16(src, &Bs[buf][r0 * DD]);
        }
    };

    stage(0, 0);
    int prev_b0 = -1;

    for (int nb = 0; nb < NSTAGE; ++nb) {
        const int cur = nb & 1;
        const int b0 = nb * BN;
        __syncthreads();          // drains async loads of Bs[cur]; WAR-protects Bs[cur^1]
        if (nb + 1 < NSTAGE) stage(nb + 1, cur ^ 1);

        // combine previous iteration's colsum (parity cur^1) while MFMA work proceeds
        if (prev_b0 >= 0 && tid < BN) {
            const float v = colsum[cur ^ 1][0][tid] + colsum[cur ^ 1][1][tid]
                          + colsum[cur ^ 1][2][tid] + colsum[cur ^ 1][3][tid];
            partial[(size_t)tile * BB + prev_b0 + tid] = relI[prev_b0 + tid] * v;
        }

        f32x4 acc[2][2];
#pragma unroll
        for (int mt = 0; mt < 2; ++mt)
#pragma unroll
            for (int nt = 0; nt < 2; ++nt)
                acc[mt][nt] = (f32x4){0.f, 0.f, 0.f, 0.f};

        // ---- K-loop: 8 steps of 16x16x32 over Bs[cur] ----
#pragma unroll
        for (int ks = 0; ks < 8; ++ks) {
            bf16x8 bfr[2];
#pragma unroll
            for (int nt = 0; nt < 2; ++nt) {
                const int col = wn * 32 + nt * 16 + lrow;
                const int g = (ks * 4 + quad) ^ (col & 7);
                bfr[nt] = *(const bf16x8*)(&Bs[cur][col * DD + g * 8]);
            }
#pragma unroll
            for (int mt = 0; mt < 2; ++mt)
#pragma unroll
                for (int nt = 0; nt < 2; ++nt)
                    acc[mt][nt] = __builtin_amdgcn_mfma_f32_16x16x32_bf16(
                        afr[ks][mt], bfr[nt], acc[mt][nt], 0, 0, 0);
        }

        // ---- epilogue: s(col) = sum_rows (G + c2) * r[b, j(row)]; quad-reduce ----
        float sv[2];
#pragma unroll
        for (int nt = 0; nt < 2; ++nt) {
            const int col = wn * 32 + nt * 16 + lrow;
            float s = 0.f;
#pragma unroll
            for (int mt = 0; mt < 2; ++mt) {
                const int e = jbase + wm * 32 + mt * 16 + quad * 4;   // j-element index
                const int g = (e >> 3) ^ (col & 7);
                const ushort4 rj = *(const ushort4*)(&Bs[cur][col * DD + g * 8 + (e & 7)]);
                s += (acc[mt][nt][0] + c2v[mt][0]) * bf2f(rj.x);
                s += (acc[mt][nt][1] + c2v[mt][1]) * bf2f(rj.y);
                s += (acc[mt][nt][2] + c2v[mt][2]) * bf2f(rj.z);
                s += (acc[mt][nt][3] + c2v[mt][3]) * bf2f(rj.w);
            }
            s += __shfl_xor(s, 16, 64);
            s += __shfl_xor(s, 32, 64);
            sv[nt] = s;
        }
        if (lane < 32) colsum[cur][wm][wn * 32 + lane] = sv[lane >> 4];
        prev_b0 = b0;
    }
    __syncthreads();
    if (tid < BN) {   // final combine, parity (NSTAGE-1)&1 = 1
        const float v = colsum[1][0][tid] + colsum[1][1][tid]
                      + colsum[1][2][tid] + colsum[1][3][tid];
        partial[(size_t)tile * BB + prev_b0 + tid] = relI[prev_b0 + tid] * v;
    }
}

// K4: out[b] += sum over 512 partial rows. 64 blocks x 256 threads.
__global__ void reduce_partial(const float* __restrict__ partial, float* __restrict__ out) {
    __shared__ f32x4 red[256];
    const int t = threadIdx.x;
    const int g = blockIdx.x * 8 + (t & 7);   // float4 column group (512 total)
    const int slice = t >> 3;                 // 32 row-slices of 16 rows
    f32x4 s = (f32x4){0.f, 0.f, 0.f, 0.f};
    for (int r = slice * 16; r < slice * 16 + 16; ++r)
        s += *(const f32x4*)(partial + (size_t)r * BB + g * 4);
    red[t] = s; __syncthreads();
    if (t < 128) red[t] += red[t + 128]; __syncthreads();
    if (t < 64)  red[t] += red[t + 64];  __syncthreads();
    if (t < 32)  red[t] += red[t + 32];  __syncthreads();
    if (t < 16)  red[t] += red[t + 16];  __syncthreads();
    if (t < 8) {
        const f32x4 v = red[t] + red[t + 8];   // final 16->8 combine (was missing in R3)
        float4* op = (float4*)(out + (size_t)(blockIdx.x * 8 + t) * 4);
        float4 o = *op;
        o.x += v[0]; o.y += v[1]; o.z += v[2]; o.w += v[3];
        *op = o;
    }
}

extern "C" void kernel_launch(void* const* d_in, const int* in_sizes, int n_in,
                              void* d_out, int out_size, void* d_ws, size_t ws_size,
                              hipStream_t stream) {
    const float* x       = (const float*)d_in[0];
    const float* offsets = (const float*)d_in[1];
    const float* c0      = (const float*)d_in[2];
    const float* c1      = (const float*)d_in[3];
    const float* c2      = (const float*)d_in[4];
    const float* c3      = (const float*)d_in[5];
    float* out = (float*)d_out;

    char* ws = (char*)d_ws;
    float* rel_f32 = (float*)ws;                                             // 2 MB
    unsigned short* rel_bf16 = (unsigned short*)(ws + (size_t)BB * DD * 4);  // 1 MB
    float* partial = (float*)(ws + (size_t)BB * DD * 6);                     // 4 MB (512 x 2048)

    prep_all<<<BB / 8, 256, 0, stream>>>(x, offsets, c0, c1, rel_f32, rel_bf16, out);
    taylor3<<<NTILE, 512, 0, stream>>>(c3, c2, rel_f32, rel_bf16, partial);
    reduce_partial<<<64, 256, 0, stream>>>(partial, out);
}